// Round 11
// baseline (185.697 us; speedup 1.0000x reference)
//
#include <hip/hip_runtime.h>

typedef __bf16 bf16x8 __attribute__((ext_vector_type(8)));
typedef float f32x4 __attribute__((ext_vector_type(4)));
typedef float f32x16 __attribute__((ext_vector_type(16)));
typedef unsigned short ushort8 __attribute__((ext_vector_type(8)));
typedef unsigned int uint4v __attribute__((ext_vector_type(4)));

#define BATCH 8
#define SEQ 4096
#define DH 128
#define NELEM 4194304ull     // BATCH*SEQ*DH
#define KSPLIT 2             // 2 planes x 2048 keys
#define NT 32                // 64-key steps per plane
#define SC (0.08838834764831845f * 1.4426950408889634f)

// ---- legacy dynamic-LDS map (u16 units), R3-proven fallback path ----
#define OFF_V 16384
#define SMEM_BYTES 75776
// ---- split kernel dynamic LDS (u16): K bufs @0,8192 (64key x 256B, swz byte^=(row&7)<<4)
//      V bufs @16384,24576 (128d x 128B rows, 16B slot ^= d&7)
#define SMEM_SPLIT 65536

__device__ __forceinline__ unsigned short f2bf(float x) {
    unsigned int u = __builtin_bit_cast(unsigned int, x);
    u = (u + 0x7FFFu + ((u >> 16) & 1u)) >> 16;
    return (unsigned short)u;
}
__device__ __forceinline__ ushort8 cvt8(const float* __restrict__ p) {
    f32x4 a = *(const f32x4*)p;
    f32x4 b = *(const f32x4*)(p + 4);
    ushort8 r;
    r[0] = f2bf(a[0]); r[1] = f2bf(a[1]); r[2] = f2bf(a[2]); r[3] = f2bf(a[3]);
    r[4] = f2bf(b[0]); r[5] = f2bf(b[1]); r[6] = f2bf(b[2]); r[7] = f2bf(b[3]);
    return r;
}
__device__ __forceinline__ ushort8 cvt8s(const float* __restrict__ p, float sc) {
    f32x4 a = *(const f32x4*)p;
    f32x4 b = *(const f32x4*)(p + 4);
    ushort8 r;
    r[0] = f2bf(a[0] * sc); r[1] = f2bf(a[1] * sc); r[2] = f2bf(a[2] * sc); r[3] = f2bf(a[3] * sc);
    r[4] = f2bf(b[0] * sc); r[5] = f2bf(b[1] * sc); r[6] = f2bf(b[2] * sc); r[7] = f2bf(b[3] * sc);
    return r;
}
__device__ __forceinline__ bf16x8 ldb(const unsigned short* p) {
    return __builtin_bit_cast(bf16x8, *(const ushort8*)p);
}
__device__ __forceinline__ void gll16(const void* src, void* dst) {
    __builtin_amdgcn_global_load_lds((const __attribute__((address_space(1))) unsigned int*)src,
                                     (__attribute__((address_space(3))) unsigned int*)dst, 16, 0, 0);
}
__device__ __forceinline__ unsigned int cvtpk(float lo, float hi) {
    unsigned int r;
    asm("v_cvt_pk_bf16_f32 %0, %1, %2" : "=v"(r) : "v"(lo), "v"(hi));
    return r;
}
__device__ __forceinline__ bf16x8 frag4(unsigned int a, unsigned int b,
                                        unsigned int c, unsigned int d) {
    uint4v u; u[0] = a; u[1] = b; u[2] = c; u[3] = d;
    return __builtin_bit_cast(bf16x8, u);
}

// ---------------- prep kernel: K->bf16 (coalesced), V->bf16 transposed (coalesced) ----
__global__ __launch_bounds__(256) void prep_all(const float* __restrict__ Kg,
                                                const float* __restrict__ Vg,
                                                unsigned short* __restrict__ Kbf,
                                                unsigned short* __restrict__ Vtg) {
    __shared__ float T[128 * 33];            // 16.9 KB, +1-pad
    if (blockIdx.x < 2048) {
        size_t i = ((size_t)blockIdx.x * 256 + threadIdx.x) * 8;
        *(ushort8*)(Kbf + i) = cvt8(Kg + i);
        return;
    }
    const int bid = blockIdx.x - 2048;       // 0..1023
    const int b  = bid >> 7;                 // batch
    const int kt = (bid >> 2) & 31;          // key tile: k0 = kt*128
    const int dt = bid & 3;                  // d tile:   d0 = dt*32
    const int tid = threadIdx.x;
    {
        const int r = tid >> 1, half = tid & 1;
        const float* src = Vg + ((size_t)b * SEQ + kt * 128 + r) * DH + dt * 32 + half * 16;
        float* dst = &T[r * 33 + half * 16];
#pragma unroll
        for (int i = 0; i < 4; ++i)
            *(f32x4*)(dst + i * 4) = *(const f32x4*)(src + i * 4);
    }
    __syncthreads();
    {
        const int d = tid >> 3, kc = (tid & 7) * 16;
        ushort8 o0, o1;
#pragma unroll
        for (int j = 0; j < 8; ++j) {
            o0[j] = f2bf(T[(kc + j) * 33 + d]);
            o1[j] = f2bf(T[(kc + 8 + j) * 33 + d]);
        }
        unsigned short* dst = Vtg + ((size_t)b * DH + dt * 32 + d) * SEQ + kt * 128 + kc;
        *(ushort8*)dst       = o0;
        *(ushort8*)(dst + 8) = o1;
    }
}

// ==================================================================================
// SPLIT-K, 64-key steps: 512 blocks (8b x 32qt x 2ks) = 2 blocks/CU, one round.
// NT=32 steps of 64 keys -> HALF the barriers/vmcnt-waits of the 32-key version,
// same per-key staging rate (8 gll/wave per 64-key step). Per step:
//   {vmcnt(0); barrier; STAGE(t+1); QK_n0 || QK_n1 (two indep 8-chains);
//    SM_PV(n0); SM_PV(n1)}  -- T15 overlap internal to the step, no s-carry.
// 2-buffer ring is race-free: all tile-t reads complete in body t, before
// barrier(t+1); STAGE(t+2) (same buf parity) issues after barrier(t+1).
// VALU diet: Q pre-scaled by SC, zro C-operand, L rowsum via mfma(pf, ones).
// ==================================================================================
__global__ __launch_bounds__(256, 2)
void attn_split(const float* __restrict__ Qg,
                const unsigned short* __restrict__ Kbf,
                const unsigned short* __restrict__ Vtg,
                float* __restrict__ Opart, float* __restrict__ Lpart)
{
    extern __shared__ __align__(16) unsigned char smem[];
    unsigned short* sm16 = (unsigned short*)smem;

    const int tid  = threadIdx.x;
    const int wv   = tid >> 6;
    const int lane = tid & 63;
    const int l32  = lane & 31;
    const int h    = lane >> 5;

    const int b  = blockIdx.x & 7;          // batch -> XCD slot (K/V L2 locality)
    const int rr = blockIdx.x >> 3;         // 0..63
    const int ks = rr & 1;
    const int qt = rr >> 1;                 // 0..31
    const int kb0 = ks * 2048;

    const int q0 = qt * 128 + wv * 32;
    const size_t qbase = (size_t)b * SEQ + q0;

    // Q as B-operand, PRE-SCALED by SC: B[k][n=q], n=l32 ; k = h*8+j per d-chunk c
    bf16x8 qf[8];
#pragma unroll
    for (int c = 0; c < 8; ++c)
        qf[c] = __builtin_bit_cast(bf16x8, cvt8s(Qg + (qbase + l32) * DH + c * 16 + h * 8, SC));

    const f32x16 zro = {0.f,0.f,0.f,0.f,0.f,0.f,0.f,0.f,0.f,0.f,0.f,0.f,0.f,0.f,0.f,0.f};
    f32x16 oacc[4];
#pragma unroll
    for (int dt = 0; dt < 4; ++dt) oacc[dt] = zro;
    f32x16 lacc = zro;                       // rowsum accumulator via mfma(pf, ones)
    ushort8 one_u;
#pragma unroll
    for (int j = 0; j < 8; ++j) one_u[j] = 0x3F80;   // bf16 1.0
    const bf16x8 ones8 = __builtin_bit_cast(bf16x8, one_u);

    const int swzK = (l32 & 7) << 4;        // K read swizzle (byte units)
    const int vsw  = l32 & 7;               // V read slot swizzle = d&7

    // persistent staging sources. Roles: wv 0,1 -> K rows wv*32..+31 ; wv 2,3 -> V d-rows (wv-2)*64..+63
    const unsigned char* srcK0 = nullptr;   // even chunks (rows ch*4+rin, ch even)
    const unsigned char* srcK1 = nullptr;   // odd chunks (+4 rows -> swizzle differs)
    const unsigned char* srcV  = nullptr;
    if (wv < 2) {
        const unsigned short* Kb = Kbf + (size_t)b * SEQ * DH;
        const int rin = lane >> 4;              // 0..3
        const int sb  = (lane & 15) << 4;
        const int r0  = wv * 32 + rin;          // chunk0 row
        const int r1  = wv * 32 + 4 + rin;      // chunk1 row
        srcK0 = (const unsigned char*)(Kb + (size_t)(kb0 + r0) * DH) + (sb ^ ((r0 & 7) << 4));
        srcK1 = (const unsigned char*)(Kb + (size_t)(kb0 + r1) * DH) + (sb ^ ((r1 & 7) << 4));
        // chunk ch (0..7): ptr = (ch&1 ? srcK1 : srcK0) + (ch>>1)*2048  (8 rows per pair)
    } else {
        const unsigned short* Vb = Vtg + (size_t)b * DH * SEQ;
        const int vr = lane >> 3;               // 0..7 row within chunk
        const int vs = lane & 7;                // linear slot
        const int row0 = (wv - 2) * 64 + vr;    // chunk0 d-row; chunk stride 8 rows (row&7 invariant)
        const int slot = vs ^ (vr & 7);         // source-side swizzle (= dest slot ^ (d&7))
        srcV = (const unsigned char*)(Vb + (size_t)row0 * SEQ + kb0 + slot * 8);
        // chunk ch: ptr = srcV + ch*65536   (8 rows x SEQ x 2B)
    }

#define STAGE(bufv)                                                                   \
    {                                                                                 \
        if (wv < 2) {                                                                 \
            unsigned short* kd = sm16 + (bufv) * 8192 + wv * 4096;                    \
            _Pragma("unroll")                                                         \
            for (int ch = 0; ch < 8; ++ch)                                            \
                gll16(((ch & 1) ? srcK1 : srcK0) + (ch >> 1) * 2048, kd + ch * 512);  \
            srcK0 += 16384; srcK1 += 16384;                                           \
        } else {                                                                      \
            unsigned short* vd = sm16 + 16384 + (bufv) * 8192 + (wv - 2) * 4096;      \
            _Pragma("unroll")                                                         \
            for (int ch = 0; ch < 8; ++ch)                                            \
                gll16(srcV + ch * 65536, vd + ch * 512);                              \
            srcV += 128;                                                              \
        }                                                                             \
    }

// softmax + PV for 32-key half N of the current tile (scores in SREG, V buf = bufc).
// p = exp2(S) (SC folded into Q); pack bf16; half-swap; L via mfma(pf, ones); 8 PV MFMA.
#define SM_PV(N, SREG)                                                              \
    {                                                                               \
        unsigned int w_[8];                                                         \
        _Pragma("unroll")                                                           \
        for (int i_ = 0; i_ < 8; ++i_) {                                            \
            float pa_ = exp2f(SREG[2 * i_]);                                        \
            float pb_ = exp2f(SREG[2 * i_ + 1]);                                    \
            w_[i_] = cvtpk(pa_, pb_);                                               \
        }                                                                           \
        unsigned int t0_ = __shfl_xor(h ? w_[0] : w_[2], 32);                       \
        unsigned int t1_ = __shfl_xor(h ? w_[1] : w_[3], 32);                       \
        unsigned int t2_ = __shfl_xor(h ? w_[4] : w_[6], 32);                       \
        unsigned int t3_ = __shfl_xor(h ? w_[5] : w_[7], 32);                       \
        bf16x8 pf0_ = frag4(h ? t0_ : w_[0], h ? t1_ : w_[1], h ? w_[2] : t0_, h ? w_[3] : t1_); \
        bf16x8 pf1_ = frag4(h ? t2_ : w_[4], h ? t3_ : w_[5], h ? w_[6] : t2_, h ? w_[7] : t3_); \
        const unsigned short* Vt_ = sm16 + 16384 + bufc * 8192;                     \
        __builtin_amdgcn_s_setprio(1);                                              \
        lacc = __builtin_amdgcn_mfma_f32_32x32x16_bf16(pf0_, ones8, lacc, 0, 0, 0); \
        lacc = __builtin_amdgcn_mfma_f32_32x32x16_bf16(pf1_, ones8, lacc, 0, 0, 0); \
        _Pragma("unroll")                                                           \
        for (int dt_ = 0; dt_ < 4; ++dt_) {                                         \
            const int d_ = dt_ * 32 + l32;                                          \
            bf16x8 v0_ = ldb(Vt_ + d_ * 64 + ((((N) * 4     + h) ^ vsw) * 8));      \
            bf16x8 v1_ = ldb(Vt_ + d_ * 64 + ((((N) * 4 + 2 + h) ^ vsw) * 8));      \
            oacc[dt_] = __builtin_amdgcn_mfma_f32_32x32x16_bf16(pf0_, v0_, oacc[dt_], 0, 0, 0); \
            oacc[dt_] = __builtin_amdgcn_mfma_f32_32x32x16_bf16(pf1_, v1_, oacc[dt_], 0, 0, 0); \
        }                                                                           \
        __builtin_amdgcn_s_setprio(0);                                              \
    }

    asm volatile("s_waitcnt vmcnt(0)" ::: "memory");   // Q loads drained
    STAGE(0);

    for (int t = 0; t < NT; ++t) {
        const int bufc = t & 1;
        asm volatile("s_waitcnt vmcnt(0)" ::: "memory");   // tile t landed (issued 1 step ago)
        __builtin_amdgcn_s_barrier();                      // visible to all waves
        asm volatile("" ::: "memory");
        if (t + 1 < NT) STAGE(bufc ^ 1);   // buf (t+1)&1: tile t-1 reads done pre-barrier

        // ---- QK(t): two independent 8-chains (key subtiles n0 rows l32, n1 rows 32+l32)
        const unsigned char* Kbb = (const unsigned char*)(sm16 + bufc * 8192);
        __builtin_amdgcn_s_setprio(1);
        f32x16 s0, s1;
        {
            bf16x8 ka = ldb((const unsigned short*)(Kbb + l32 * 256        + ((h * 16) ^ swzK)));
            bf16x8 kb = ldb((const unsigned short*)(Kbb + (32 + l32) * 256 + ((h * 16) ^ swzK)));
            s0 = __builtin_amdgcn_mfma_f32_32x32x16_bf16(ka, qf[0], zro, 0, 0, 0);
            s1 = __builtin_amdgcn_mfma_f32_32x32x16_bf16(kb, qf[0], zro, 0, 0, 0);
        }
#pragma unroll
        for (int c = 1; c < 8; ++c) {
            bf16x8 ka = ldb((const unsigned short*)(Kbb + l32 * 256        + ((c * 32 + h * 16) ^ swzK)));
            bf16x8 kb = ldb((const unsigned short*)(Kbb + (32 + l32) * 256 + ((c * 32 + h * 16) ^ swzK)));
            s0 = __builtin_amdgcn_mfma_f32_32x32x16_bf16(ka, qf[c], s0, 0, 0, 0);
            s1 = __builtin_amdgcn_mfma_f32_32x32x16_bf16(kb, qf[c], s1, 0, 0, 0);
        }
        __builtin_amdgcn_s_setprio(0);

        // ---- softmax+PV both halves; SM_PV(n0)'s MFMAs hide s1's chain tail
        SM_PV(0, s0)
        SM_PV(1, s1)
    }
#undef STAGE
#undef SM_PV

    // ---- write partials: numerator (f32) + rowsum L (lacc cols all equal)
    if (l32 == 0) {
#pragma unroll
        for (int r = 0; r < 16; ++r) {
            const int qr = (r & 3) + 8 * (r >> 2) + 4 * h;
            Lpart[(size_t)ks * (BATCH * SEQ) + (size_t)b * SEQ + q0 + qr] = lacc[r];
        }
    }
    float* Op = Opart + (size_t)ks * NELEM;
#pragma unroll
    for (int dt = 0; dt < 4; ++dt)
#pragma unroll
        for (int r = 0; r < 16; ++r) {
            const int qr = (r & 3) + 8 * (r >> 2) + 4 * h;
            Op[(qbase + qr) * DH + dt * 32 + l32] = oacc[dt][r];
        }
}

// merge the 2 ks-planes: O = (sum Op) / (sum L)
__global__ __launch_bounds__(256)
void merge_split(const float* __restrict__ Opart, const float* __restrict__ Lpart,
                 float* __restrict__ O)
{
    const size_t g  = (size_t)blockIdx.x * 256 + threadIdx.x;   // 1,048,576 threads
    const size_t i4 = g * 4;
    const size_t bq = i4 >> 7;                                  // b*SEQ + q
    float L = Lpart[bq] + Lpart[BATCH * SEQ + bq];
    const float inv = 1.0f / L;
    f32x4 a  = *(const f32x4*)&Opart[i4];
    f32x4 b1 = *(const f32x4*)&Opart[NELEM + i4];
#pragma unroll
    for (int j = 0; j < 4; ++j) a[j] = (a[j] + b1[j]) * inv;
    *(f32x4*)&O[i4] = a;
}

// ==================================================================================
// LEGACY PATH (R3-proven): used only when ws is too small for split-K partials.
// ==================================================================================
__device__ __forceinline__ void stage_fallback(const float* __restrict__ Kg,
                                               const float* __restrict__ Vg,
                                               unsigned short* sm16, int b, int tid, int t)
{
    const int buf = t & 1;
#pragma unroll
    for (int s = 0; s < 2; ++s) {
        const int kb = s * 2048 + t * 32;
        {
            int r = tid >> 3, cg = tid & 7;
            const float* sp = Kg + ((size_t)b * SEQ + kb + r) * DH + cg * 16;
            ushort8 lo = cvt8(sp), hi = cvt8(sp + 8);
            unsigned char* kd = (unsigned char*)(sm16 + (s * 2 + buf) * 4096) + r * 256;
            int sbb = cg * 32, m = (r & 7) << 4;
            *(ushort8*)(kd + (sbb ^ m))        = lo;
            *(ushort8*)(kd + ((sbb + 16) ^ m)) = hi;
        }
        {
            int d = tid >> 1, half = tid & 1, sw = (d >> 1) & 3;
            ushort8 a, c;
#pragma unroll
            for (int j = 0; j < 8; ++j) {
                a[j] = f2bf(Vg[((size_t)b * SEQ + kb + half * 16 + j) * DH + d]);
                c[j] = f2bf(Vg[((size_t)b * SEQ + kb + half * 16 + 8 + j) * DH + d]);
            }
            unsigned short* vd = sm16 + OFF_V + (s * 2 + buf) * 4096 + d * 32;
            *(ushort8*)(vd + ((half * 2    ) ^ sw) * 8) = a;
            *(ushort8*)(vd + ((half * 2 + 1) ^ sw) * 8) = c;
        }
    }
}

__global__ __launch_bounds__(256, 2)
void attn_fwd(const float* __restrict__ Qg, const float* __restrict__ Kg,
              const float* __restrict__ Vg, float* __restrict__ Og)
{
    extern __shared__ __align__(16) unsigned char smem[];
    unsigned short* sm16 = (unsigned short*)smem;

    const int tid  = threadIdx.x;
    const int wv   = tid >> 6;
    const int lane = tid & 63;
    const int l32  = lane & 31;
    const int h    = lane >> 5;
    const int qh = wv & 1;
    const int kh = wv >> 1;
    const int b   = blockIdx.x & 7;
    const int qt5 = blockIdx.x >> 3;

    const size_t qbase = (size_t)b * SEQ + (size_t)qt5 * 64 + qh * 32;

    bf16x8 qf[8];
#pragma unroll
    for (int c = 0; c < 8; ++c)
        qf[c] = __builtin_bit_cast(bf16x8, cvt8(Qg + (qbase + l32) * DH + c * 16 + h * 8));

    f32x16 oacc[4];
#pragma unroll
    for (int dt = 0; dt < 4; ++dt)
#pragma unroll
        for (int r = 0; r < 16; ++r) oacc[dt][r] = 0.f;
    float lpA = 0.f, lpB = 0.f;
    const int swzK = (l32 & 7) << 4;

    asm volatile("s_waitcnt vmcnt(0)" ::: "memory");
    stage_fallback(Kg, Vg, sm16, b, tid, 0);

    for (int t = 0; t < 64; ++t) {
        __builtin_amdgcn_s_barrier();
        asm volatile("" ::: "memory");
        if (t < 63) stage_fallback(Kg, Vg, sm16, b, tid, t + 1);
        asm volatile("s_waitcnt vmcnt(0) lgkmcnt(0)" ::: "memory");
        __builtin_amdgcn_s_barrier();
        asm volatile("" ::: "memory");

        const unsigned char*  Kbb = (const unsigned char*)(sm16 + (kh * 2 + (t & 1)) * 4096);
        const unsigned short* Vt  = sm16 + OFF_V + (kh * 2 + (t & 1)) * 4096;

        f32x16 s;
#pragma unroll
        for (int r = 0; r < 16; ++r) s[r] = 0.f;
#pragma unroll
        for (int c = 0; c < 8; ++c) {
            bf16x8 kf = ldb((const unsigned short*)(Kbb + l32 * 256 + ((c * 32 + h * 16) ^ swzK)));
            s = __builtin_amdgcn_mfma_f32_32x32x16_bf16(kf, qf[c], s, 0, 0, 0);
        }

        unsigned int w[8];
#pragma unroll
        for (int i = 0; i < 8; ++i) {
            float pa = exp2f(s[2 * i]     * SC);
            float pb = exp2f(s[2 * i + 1] * SC);
            lpA += pa; lpB += pb;
            w[i] = cvtpk(pa, pb);
        }
        unsigned int t0 = __shfl_xor(h ? w[0] : w[2], 32);
        unsigned int t1 = __shfl_xor(h ? w[1] : w[3], 32);
        unsigned int t2 = __shfl_xor(h ? w[4] : w[6], 32);
        unsigned int t3 = __shfl_xor(h ? w[5] : w[7], 32);
        bf16x8 pf0 = frag4(h ? t0 : w[0], h ? t1 : w[1], h ? w[2] : t0, h ? w[3] : t1);
        bf16x8 pf1 = frag4(h ? t2 : w[4], h ? t3 : w[5], h ? w[6] : t2, h ? w[7] : t3);

#pragma unroll
        for (int dt = 0; dt < 4; ++dt) {
            const int d  = dt * 32 + l32;
            const int sw = (d >> 1) & 3;
            bf16x8 v0 = ldb(Vt + d * 32 + ((h    ) ^ sw) * 8);
            bf16x8 v1 = ldb(Vt + d * 32 + ((2 + h) ^ sw) * 8);
            oacc[dt] = __builtin_amdgcn_mfma_f32_32x32x16_bf16(pf0, v0, oacc[dt], 0, 0, 0);
            oacc[dt] = __builtin_amdgcn_mfma_f32_32x32x16_bf16(pf1, v1, oacc[dt], 0, 0, 0);
        }
    }

    float lp2 = lpA + lpB;
    lp2 += __shfl_xor(lp2, 32);
    float* Om = (float*)sm16;
    float* lb = (float*)((char*)sm16 + 65536);
    __syncthreads();
    if (h == 0) lb[kh * 64 + qh * 32 + l32] = lp2;
    if (kh == 1) {
#pragma unroll
        for (int dt = 0; dt < 4; ++dt)
#pragma unroll
            for (int r = 0; r < 16; ++r) {
                const int qr = (r & 3) + 8 * (r >> 2) + 4 * h;
                Om[(qh * 32 + qr) * 128 + dt * 32 + l32] = oacc[dt][r];
            }
    }
    __syncthreads();
    if (kh == 0) {
        float invr[16];
#pragma unroll
        for (int r = 0; r < 16; ++r) {
            const int qr = (r & 3) + 8 * (r >> 2) + 4 * h;
            invr[r] = 1.0f / (lb[qh * 32 + qr] + lb[64 + qh * 32 + qr]);
        }
#pragma unroll
        for (int dt = 0; dt < 4; ++dt)
#pragma unroll
            for (int r = 0; r < 16; ++r) {
                const int qr = (r & 3) + 8 * (r >> 2) + 4 * h;
                Og[(qbase + qr) * DH + dt * 32 + l32] =
                    (oacc[dt][r] + Om[(qh * 32 + qr) * 128 + dt * 32 + l32]) * invr[r];
            }
    }
}

extern "C" void kernel_launch(void* const* d_in, const int* in_sizes, int n_in,
                              void* d_out, int out_size, void* d_ws, size_t ws_size,
                              hipStream_t stream) {
    const float* Q = (const float*)d_in[0];
    const float* K = (const float*)d_in[1];
    const float* V = (const float*)d_in[2];
    float* O = (float*)d_out;

    const size_t prep_bytes  = NELEM * 2 * 2;                          // 16,777,216
    const size_t split_bytes = prep_bytes + KSPLIT * NELEM * 4         // partials (33.6 MB)
                             + (size_t)KSPLIT * BATCH * SEQ * 4;       // L (0.26 MB)
    const bool prep  = (ws_size >= prep_bytes);
    const bool split = (ws_size >= split_bytes);

    unsigned short* Kbf = (unsigned short*)d_ws;
    unsigned short* Vtg = Kbf + NELEM;
    float* Opart = (float*)(Kbf + 2 * NELEM);
    float* Lpart = Opart + KSPLIT * NELEM;

    static int smem_cfged = 0;
    if (!smem_cfged) {
        (void)hipFuncSetAttribute((const void*)attn_fwd,
                                  hipFuncAttributeMaxDynamicSharedMemorySize, SMEM_BYTES);
        (void)hipFuncSetAttribute((const void*)attn_split,
                                  hipFuncAttributeMaxDynamicSharedMemorySize, SMEM_SPLIT);
        smem_cfged = 1;
    }

    if (prep && split) {
        prep_all<<<dim3(2048 + BATCH * 32 * 4), 256, 0, stream>>>(K, V, Kbf, Vtg);
        attn_split<<<dim3(BATCH * 32 * KSPLIT), 256, SMEM_SPLIT, stream>>>(Q, Kbf, Vtg, Opart, Lpart);
        merge_split<<<dim3(NELEM / (256 * 4)), 256, 0, stream>>>(Opart, Lpart, O);
    } else {
        attn_fwd<<<dim3(BATCH * (SEQ / 64)), 256, SMEM_BYTES, stream>>>(Q, K, V, O);
    }
}

// Round 12
// 180.708 us; speedup vs baseline: 1.0276x; 1.0276x over previous
//
#include <hip/hip_runtime.h>

typedef __bf16 bf16x8 __attribute__((ext_vector_type(8)));
typedef float f32x4 __attribute__((ext_vector_type(4)));
typedef float f32x16 __attribute__((ext_vector_type(16)));
typedef unsigned short ushort8 __attribute__((ext_vector_type(8)));
typedef unsigned int uint4v __attribute__((ext_vector_type(4)));

#define BATCH 8
#define SEQ 4096
#define DH 128
#define NELEM 4194304ull     // BATCH*SEQ*DH
#define KSPLIT 2             // 2 planes x 2048 keys
#define NT 64                // 32-key steps per plane
#define SC (0.08838834764831845f * 1.4426950408889634f)

// ---- legacy dynamic-LDS map (u16 units), R3-proven fallback path ----
#define OFF_V 16384
#define SMEM_BYTES 75776
// ---- split kernel dynamic LDS: 4-buf ring, K bufs [0..16383], V bufs [16384..32767] u16
#define SMEM_SPLIT 65536

__device__ __forceinline__ unsigned short f2bf(float x) {
    unsigned int u = __builtin_bit_cast(unsigned int, x);
    u = (u + 0x7FFFu + ((u >> 16) & 1u)) >> 16;
    return (unsigned short)u;
}
__device__ __forceinline__ ushort8 cvt8(const float* __restrict__ p) {
    f32x4 a = *(const f32x4*)p;
    f32x4 b = *(const f32x4*)(p + 4);
    ushort8 r;
    r[0] = f2bf(a[0]); r[1] = f2bf(a[1]); r[2] = f2bf(a[2]); r[3] = f2bf(a[3]);
    r[4] = f2bf(b[0]); r[5] = f2bf(b[1]); r[6] = f2bf(b[2]); r[7] = f2bf(b[3]);
    return r;
}
__device__ __forceinline__ ushort8 cvt8s(const float* __restrict__ p, float sc) {
    f32x4 a = *(const f32x4*)p;
    f32x4 b = *(const f32x4*)(p + 4);
    ushort8 r;
    r[0] = f2bf(a[0] * sc); r[1] = f2bf(a[1] * sc); r[2] = f2bf(a[2] * sc); r[3] = f2bf(a[3] * sc);
    r[4] = f2bf(b[0] * sc); r[5] = f2bf(b[1] * sc); r[6] = f2bf(b[2] * sc); r[7] = f2bf(b[3] * sc);
    return r;
}
__device__ __forceinline__ bf16x8 ldb(const unsigned short* p) {
    return __builtin_bit_cast(bf16x8, *(const ushort8*)p);
}
__device__ __forceinline__ void gll16(const void* src, void* dst) {
    __builtin_amdgcn_global_load_lds((const __attribute__((address_space(1))) unsigned int*)src,
                                     (__attribute__((address_space(3))) unsigned int*)dst, 16, 0, 0);
}
__device__ __forceinline__ unsigned int cvtpk(float lo, float hi) {
    unsigned int r;
    asm("v_cvt_pk_bf16_f32 %0, %1, %2" : "=v"(r) : "v"(lo), "v"(hi));
    return r;
}
__device__ __forceinline__ void plswap(unsigned int& a, unsigned int& b) {
    asm volatile("v_permlane32_swap_b32 %0, %1" : "+v"(a), "+v"(b));
}
__device__ __forceinline__ bf16x8 frag4(unsigned int a, unsigned int b,
                                        unsigned int c, unsigned int d) {
    uint4v u; u[0] = a; u[1] = b; u[2] = c; u[3] = d;
    return __builtin_bit_cast(bf16x8, u);
}

// ---------------- prep kernel: K->bf16 (coalesced), V->bf16 transposed (coalesced) ----
__global__ __launch_bounds__(256) void prep_all(const float* __restrict__ Kg,
                                                const float* __restrict__ Vg,
                                                unsigned short* __restrict__ Kbf,
                                                unsigned short* __restrict__ Vtg) {
    __shared__ float T[128 * 33];            // 16.9 KB, +1-pad
    if (blockIdx.x < 2048) {
        size_t i = ((size_t)blockIdx.x * 256 + threadIdx.x) * 8;
        *(ushort8*)(Kbf + i) = cvt8(Kg + i);
        return;
    }
    const int bid = blockIdx.x - 2048;       // 0..1023
    const int b  = bid >> 7;                 // batch
    const int kt = (bid >> 2) & 31;          // key tile: k0 = kt*128
    const int dt = bid & 3;                  // d tile:   d0 = dt*32
    const int tid = threadIdx.x;
    {
        const int r = tid >> 1, half = tid & 1;
        const float* src = Vg + ((size_t)b * SEQ + kt * 128 + r) * DH + dt * 32 + half * 16;
        float* dst = &T[r * 33 + half * 16];
#pragma unroll
        for (int i = 0; i < 4; ++i)
            *(f32x4*)(dst + i * 4) = *(const f32x4*)(src + i * 4);
    }
    __syncthreads();
    {
        const int d = tid >> 3, kc = (tid & 7) * 16;
        ushort8 o0, o1;
#pragma unroll
        for (int j = 0; j < 8; ++j) {
            o0[j] = f2bf(T[(kc + j) * 33 + d]);
            o1[j] = f2bf(T[(kc + 8 + j) * 33 + d]);
        }
        unsigned short* dst = Vtg + ((size_t)b * DH + dt * 32 + d) * SEQ + kt * 128 + kc;
        *(ushort8*)dst       = o0;
        *(ushort8*)(dst + 8) = o1;
    }
}

// ==================================================================================
// SPLIT-K (R10-proven structure, 95.5us): 512 blocks (8b x 32qt x 2ks) = 2 blocks/CU.
// T15 2-tile pipeline: QK(t) || softmax+PV(t-1). 4-buffer LDS ring (64KB), 2-deep
// prefetch, one barrier + vmcnt(4)/step. VALU diet: Q pre-scaled by SC, zro C-operand,
// row-sum L via mfma(pf, ones). NEW (R12): P half-exchange via v_permlane32_swap_b32
// (1 instr replaces shfl_xor + 4 cndmask per word-pair); swap direction resolved by a
// runtime probe, so both ISA semantics produce correct fragments.
// LDS map (u16): K[buf] at buf*4096 (32 key-rows x 256B, src-swz byte^=(row&7)<<4)
//                V[buf] at 16384+buf*4096 (128 d-rows x 64B, slot^=(row>>1)&3)
// ==================================================================================
__global__ __launch_bounds__(256, 2)
void attn_split(const float* __restrict__ Qg,
                const unsigned short* __restrict__ Kbf,
                const unsigned short* __restrict__ Vtg,
                float* __restrict__ Opart, float* __restrict__ Lpart)
{
    extern __shared__ __align__(16) unsigned char smem[];
    unsigned short* sm16 = (unsigned short*)smem;

    const int tid  = threadIdx.x;
    const int wv   = tid >> 6;
    const int lane = tid & 63;
    const int l32  = lane & 31;
    const int h    = lane >> 5;

    const int b  = blockIdx.x & 7;          // batch -> XCD slot (K/V L2 locality)
    const int rr = blockIdx.x >> 3;         // 0..63
    const int ks = rr & 1;
    const int qt = rr >> 1;                 // 0..31
    const int kb0 = ks * 2048;

    const int q0 = qt * 128 + wv * 32;
    const size_t qbase = (size_t)b * SEQ + q0;

    // permlane32_swap direction probe: pa=lane, pb=100+lane; after swap,
    // pa[32]==100 iff semantics are hi(A)<->lo(B) ("dir2"). Wave-uniform.
    bool dir2;
    {
        unsigned int pa = (unsigned int)lane, pb = 100u + (unsigned int)lane;
        plswap(pa, pb);
        dir2 = (__shfl((int)pa, 32) == 100);
    }

    // Q as B-operand, PRE-SCALED by SC: B[k][n=q], n=l32 ; k = h*8+j per d-chunk c
    bf16x8 qf[8];
#pragma unroll
    for (int c = 0; c < 8; ++c)
        qf[c] = __builtin_bit_cast(bf16x8, cvt8s(Qg + (qbase + l32) * DH + c * 16 + h * 8, SC));

    const f32x16 zro = {0.f,0.f,0.f,0.f,0.f,0.f,0.f,0.f,0.f,0.f,0.f,0.f,0.f,0.f,0.f,0.f};
    f32x16 oacc[4];
#pragma unroll
    for (int dt = 0; dt < 4; ++dt) oacc[dt] = zro;
    f32x16 lacc = zro;                       // rowsum accumulator via mfma(pf, ones)
    ushort8 one_u;
#pragma unroll
    for (int j = 0; j < 8; ++j) one_u[j] = 0x3F80;   // bf16 1.0
    const bf16x8 ones8 = __builtin_bit_cast(bf16x8, one_u);

    const int swzK = (l32 & 7) << 4;

    // persistent staging source pointers (role by wave: wv<2 -> K halves, else V halves)
    const unsigned char* srcp[4];
    long sstr;
    if (wv < 2) {
        const unsigned short* Kb = Kbf + (size_t)b * SEQ * DH;
#pragma unroll
        for (int ch = 0; ch < 4; ++ch) {
            const int row  = wv * 16 + ch * 4 + (lane >> 4);
            const int colb = ((lane & 15) << 4) ^ ((row & 7) << 4);
            srcp[ch] = (const unsigned char*)(Kb + (size_t)(kb0 + row) * DH) + colb;
        }
        sstr = 32 * DH * 2;        // 8192 B per step
    } else {
        const unsigned short* Vb = Vtg + (size_t)b * DH * SEQ;
#pragma unroll
        for (int ch = 0; ch < 4; ++ch) {
            const int row  = (wv - 2) * 64 + ch * 16 + (lane >> 2);
            const int slot = (lane & 3) ^ ((row >> 1) & 3);
            srcp[ch] = (const unsigned char*)(Vb + (size_t)row * SEQ + kb0 + slot * 8);
        }
        sstr = 64;                 // 32 keys * 2 B per step
    }

#define STAGE(bufv)                                                                 \
    {                                                                               \
        unsigned short* bse = (wv < 2)                                              \
            ? sm16 + (bufv) * 4096 + wv * 2048                                      \
            : sm16 + 16384 + (bufv) * 4096 + (wv - 2) * 2048;                       \
        _Pragma("unroll")                                                           \
        for (int ch = 0; ch < 4; ++ch) {                                            \
            gll16(srcp[ch], bse + ch * 512);                                        \
            srcp[ch] += sstr;                                                       \
        }                                                                           \
    }

// QK phase for tile T: wait own tile-T loads (NW=4: tile T+1 stays in flight),
// barrier (block-wide visibility), 8 MFMA into CUR (zro C-operand, no acc-zeroing),
// then issue stage of tile T+2.
#define QK_PHASE(T, CUR, NW)                                                        \
    {                                                                               \
        asm volatile("s_waitcnt vmcnt(" #NW ")" ::: "memory");                      \
        __builtin_amdgcn_s_barrier();                                               \
        asm volatile("" ::: "memory");                                              \
        const unsigned char* Kbb_ = (const unsigned char*)(sm16 + ((T) & 3) * 4096);\
        __builtin_amdgcn_s_setprio(1);                                              \
        {                                                                           \
            bf16x8 kf_ = ldb((const unsigned short*)(Kbb_ + l32 * 256 + ((h * 16) ^ swzK))); \
            CUR = __builtin_amdgcn_mfma_f32_32x32x16_bf16(kf_, qf[0], zro, 0, 0, 0);\
        }                                                                           \
        _Pragma("unroll")                                                           \
        for (int c_ = 1; c_ < 8; ++c_) {                                            \
            bf16x8 kf_ = ldb((const unsigned short*)(Kbb_ + l32 * 256 + ((c_ * 32 + h * 16) ^ swzK))); \
            CUR = __builtin_amdgcn_mfma_f32_32x32x16_bf16(kf_, qf[c_], CUR, 0, 0, 0);\
        }                                                                           \
        __builtin_amdgcn_s_setprio(0);                                              \
        if ((T) + 2 < NT) { STAGE(((T) + 2) & 3); }                                 \
    }

// softmax + PV for tile T (scores in PREV): p = exp2(S) (SC folded into Q),
// pack to bf16, permlane half-exchange, L-rowsum via mfma(pf, ones), 8 PV MFMA.
// After the swaps: w0..w3 are words 0..3 of pf0, w4..w7 are words 0..3 of pf1.
#define SM_PV(T, PREV)                                                              \
    {                                                                               \
        unsigned int w_[8];                                                         \
        _Pragma("unroll")                                                           \
        for (int i_ = 0; i_ < 8; ++i_) {                                            \
            float pa_ = exp2f(PREV[2 * i_]);                                        \
            float pb_ = exp2f(PREV[2 * i_ + 1]);                                    \
            w_[i_] = cvtpk(pa_, pb_);                                               \
        }                                                                           \
        if (dir2) {                                                                 \
            plswap(w_[0], w_[2]); plswap(w_[1], w_[3]);                             \
            plswap(w_[4], w_[6]); plswap(w_[5], w_[7]);                             \
        } else {                                                                    \
            plswap(w_[2], w_[0]); plswap(w_[3], w_[1]);                             \
            plswap(w_[6], w_[4]); plswap(w_[7], w_[5]);                             \
        }                                                                           \
        bf16x8 pf0_ = frag4(w_[0], w_[1], w_[2], w_[3]);                            \
        bf16x8 pf1_ = frag4(w_[4], w_[5], w_[6], w_[7]);                            \
        const unsigned short* Vt_ = sm16 + 16384 + ((T) & 3) * 4096;                \
        __builtin_amdgcn_s_setprio(1);                                              \
        lacc = __builtin_amdgcn_mfma_f32_32x32x16_bf16(pf0_, ones8, lacc, 0, 0, 0); \
        lacc = __builtin_amdgcn_mfma_f32_32x32x16_bf16(pf1_, ones8, lacc, 0, 0, 0); \
        _Pragma("unroll")                                                           \
        for (int dt_ = 0; dt_ < 4; ++dt_) {                                         \
            const int d_  = dt_ * 32 + l32;                                         \
            const int sw_ = (d_ >> 1) & 3;                                          \
            bf16x8 v0_ = ldb(Vt_ + d_ * 32 + ((h    ) ^ sw_) * 8);                  \
            bf16x8 v1_ = ldb(Vt_ + d_ * 32 + ((2 + h) ^ sw_) * 8);                  \
            oacc[dt_] = __builtin_amdgcn_mfma_f32_32x32x16_bf16(pf0_, v0_, oacc[dt_], 0, 0, 0); \
            oacc[dt_] = __builtin_amdgcn_mfma_f32_32x32x16_bf16(pf1_, v1_, oacc[dt_], 0, 0, 0); \
        }                                                                           \
        __builtin_amdgcn_s_setprio(0);                                              \
    }

    asm volatile("s_waitcnt vmcnt(0)" ::: "memory");   // Q loads drained
    STAGE(0);
    STAGE(1);

    f32x16 sA, sB;
    QK_PHASE(0, sA, 4)
    for (int t = 1; t < NT - 1; t += 2) {
        QK_PHASE(t, sB, 4)
        SM_PV(t - 1, sA)
        QK_PHASE(t + 1, sA, 4)
        SM_PV(t, sB)
    }
    QK_PHASE(NT - 1, sB, 0)
    SM_PV(NT - 2, sA)
    SM_PV(NT - 1, sB)
#undef STAGE
#undef QK_PHASE
#undef SM_PV

    // ---- write partials: numerator (f32) + rowsum L (lacc cols all equal)
    if (l32 == 0) {
#pragma unroll
        for (int r = 0; r < 16; ++r) {
            const int qr = (r & 3) + 8 * (r >> 2) + 4 * h;
            Lpart[(size_t)ks * (BATCH * SEQ) + (size_t)b * SEQ + q0 + qr] = lacc[r];
        }
    }
    float* Op = Opart + (size_t)ks * NELEM;
#pragma unroll
    for (int dt = 0; dt < 4; ++dt)
#pragma unroll
        for (int r = 0; r < 16; ++r) {
            const int qr = (r & 3) + 8 * (r >> 2) + 4 * h;
            Op[(qbase + qr) * DH + dt * 32 + l32] = oacc[dt][r];
        }
}

// merge the 2 ks-planes: O = (sum Op) / (sum L)
__global__ __launch_bounds__(256)
void merge_split(const float* __restrict__ Opart, const float* __restrict__ Lpart,
                 float* __restrict__ O)
{
    const size_t g  = (size_t)blockIdx.x * 256 + threadIdx.x;   // 1,048,576 threads
    const size_t i4 = g * 4;
    const size_t bq = i4 >> 7;                                  // b*SEQ + q
    float L = Lpart[bq] + Lpart[BATCH * SEQ + bq];
    const float inv = 1.0f / L;
    f32x4 a  = *(const f32x4*)&Opart[i4];
    f32x4 b1 = *(const f32x4*)&Opart[NELEM + i4];
#pragma unroll
    for (int j = 0; j < 4; ++j) a[j] = (a[j] + b1[j]) * inv;
    *(f32x4*)&O[i4] = a;
}

// ==================================================================================
// LEGACY PATH (R3-proven): used only when ws is too small for split-K partials.
// ==================================================================================
__device__ __forceinline__ void stage_fallback(const float* __restrict__ Kg,
                                               const float* __restrict__ Vg,
                                               unsigned short* sm16, int b, int tid, int t)
{
    const int buf = t & 1;
#pragma unroll
    for (int s = 0; s < 2; ++s) {
        const int kb = s * 2048 + t * 32;
        {
            int r = tid >> 3, cg = tid & 7;
            const float* sp = Kg + ((size_t)b * SEQ + kb + r) * DH + cg * 16;
            ushort8 lo = cvt8(sp), hi = cvt8(sp + 8);
            unsigned char* kd = (unsigned char*)(sm16 + (s * 2 + buf) * 4096) + r * 256;
            int sbb = cg * 32, m = (r & 7) << 4;
            *(ushort8*)(kd + (sbb ^ m))        = lo;
            *(ushort8*)(kd + ((sbb + 16) ^ m)) = hi;
        }
        {
            int d = tid >> 1, half = tid & 1, sw = (d >> 1) & 3;
            ushort8 a, c;
#pragma unroll
            for (int j = 0; j < 8; ++j) {
                a[j] = f2bf(Vg[((size_t)b * SEQ + kb + half * 16 + j) * DH + d]);
                c[j] = f2bf(Vg[((size_t)b * SEQ + kb + half * 16 + 8 + j) * DH + d]);
            }
            unsigned short* vd = sm16 + OFF_V + (s * 2 + buf) * 4096 + d * 32;
            *(ushort8*)(vd + ((half * 2    ) ^ sw) * 8) = a;
            *(ushort8*)(vd + ((half * 2 + 1) ^ sw) * 8) = c;
        }
    }
}

__global__ __launch_bounds__(256, 2)
void attn_fwd(const float* __restrict__ Qg, const float* __restrict__ Kg,
              const float* __restrict__ Vg, float* __restrict__ Og)
{
    extern __shared__ __align__(16) unsigned char smem[];
    unsigned short* sm16 = (unsigned short*)smem;

    const int tid  = threadIdx.x;
    const int wv   = tid >> 6;
    const int lane = tid & 63;
    const int l32  = lane & 31;
    const int h    = lane >> 5;
    const int qh = wv & 1;
    const int kh = wv >> 1;
    const int b   = blockIdx.x & 7;
    const int qt5 = blockIdx.x >> 3;

    const size_t qbase = (size_t)b * SEQ + (size_t)qt5 * 64 + qh * 32;

    bf16x8 qf[8];
#pragma unroll
    for (int c = 0; c < 8; ++c)
        qf[c] = __builtin_bit_cast(bf16x8, cvt8(Qg + (qbase + l32) * DH + c * 16 + h * 8));

    f32x16 oacc[4];
#pragma unroll
    for (int dt = 0; dt < 4; ++dt)
#pragma unroll
        for (int r = 0; r < 16; ++r) oacc[dt][r] = 0.f;
    float lpA = 0.f, lpB = 0.f;
    const int swzK = (l32 & 7) << 4;

    asm volatile("s_waitcnt vmcnt(0)" ::: "memory");
    stage_fallback(Kg, Vg, sm16, b, tid, 0);

    for (int t = 0; t < 64; ++t) {
        __builtin_amdgcn_s_barrier();
        asm volatile("" ::: "memory");
        if (t < 63) stage_fallback(Kg, Vg, sm16, b, tid, t + 1);
        asm volatile("s_waitcnt vmcnt(0) lgkmcnt(0)" ::: "memory");
        __builtin_amdgcn_s_barrier();
        asm volatile("" ::: "memory");

        const unsigned char*  Kbb = (const unsigned char*)(sm16 + (kh * 2 + (t & 1)) * 4096);
        const unsigned short* Vt  = sm16 + OFF_V + (kh * 2 + (t & 1)) * 4096;

        f32x16 s;
#pragma unroll
        for (int r = 0; r < 16; ++r) s[r] = 0.f;
#pragma unroll
        for (int c = 0; c < 8; ++c) {
            bf16x8 kf = ldb((const unsigned short*)(Kbb + l32 * 256 + ((c * 32 + h * 16) ^ swzK)));
            s = __builtin_amdgcn_mfma_f32_32x32x16_bf16(kf, qf[c], s, 0, 0, 0);
        }

        unsigned int w[8];
#pragma unroll
        for (int i = 0; i < 8; ++i) {
            float pa = exp2f(s[2 * i]     * SC);
            float pb = exp2f(s[2 * i + 1] * SC);
            lpA += pa; lpB += pb;
            w[i] = cvtpk(pa, pb);
        }
        unsigned int t0 = __shfl_xor(h ? w[0] : w[2], 32);
        unsigned int t1 = __shfl_xor(h ? w[1] : w[3], 32);
        unsigned int t2 = __shfl_xor(h ? w[4] : w[6], 32);
        unsigned int t3 = __shfl_xor(h ? w[5] : w[7], 32);
        bf16x8 pf0 = frag4(h ? t0 : w[0], h ? t1 : w[1], h ? w[2] : t0, h ? w[3] : t1);
        bf16x8 pf1 = frag4(h ? t2 : w[4], h ? t3 : w[5], h ? w[6] : t2, h ? w[7] : t3);

#pragma unroll
        for (int dt = 0; dt < 4; ++dt) {
            const int d  = dt * 32 + l32;
            const int sw = (d >> 1) & 3;
            bf16x8 v0 = ldb(Vt + d * 32 + ((h    ) ^ sw) * 8);
            bf16x8 v1 = ldb(Vt + d * 32 + ((2 + h) ^ sw) * 8);
            oacc[dt] = __builtin_amdgcn_mfma_f32_32x32x16_bf16(pf0, v0, oacc[dt], 0, 0, 0);
            oacc[dt] = __builtin_amdgcn_mfma_f32_32x32x16_bf16(pf1, v1, oacc[dt], 0, 0, 0);
        }
    }

    float lp2 = lpA + lpB;
    lp2 += __shfl_xor(lp2, 32);
    float* Om = (float*)sm16;
    float* lb = (float*)((char*)sm16 + 65536);
    __syncthreads();
    if (h == 0) lb[kh * 64 + qh * 32 + l32] = lp2;
    if (kh == 1) {
#pragma unroll
        for (int dt = 0; dt < 4; ++dt)
#pragma unroll
            for (int r = 0; r < 16; ++r) {
                const int qr = (r & 3) + 8 * (r >> 2) + 4 * h;
                Om[(qh * 32 + qr) * 128 + dt * 32 + l32] = oacc[dt][r];
            }
    }
    __syncthreads();
    if (kh == 0) {
        float invr[16];
#pragma unroll
        for (int r = 0; r < 16; ++r) {
            const int qr = (r & 3) + 8 * (r >> 2) + 4 * h;
            invr[r] = 1.0f / (lb[qh * 32 + qr] + lb[64 + qh * 32 + qr]);
        }
#pragma unroll
        for (int dt = 0; dt < 4; ++dt)
#pragma unroll
            for (int r = 0; r < 16; ++r) {
                const int qr = (r & 3) + 8 * (r >> 2) + 4 * h;
                Og[(qbase + qr) * DH + dt * 32 + l32] =
                    (oacc[dt][r] + Om[(qh * 32 + qr) * 128 + dt * 32 + l32]) * invr[r];
            }
    }
}

extern "C" void kernel_launch(void* const* d_in, const int* in_sizes, int n_in,
                              void* d_out, int out_size, void* d_ws, size_t ws_size,
                              hipStream_t stream) {
    const float* Q = (const float*)d_in[0];
    const float* K = (const float*)d_in[1];
    const float* V = (const float*)d_in[2];
    float* O = (float*)d_out;

    const size_t prep_bytes  = NELEM * 2 * 2;                          // 16,777,216
    const size_t split_bytes = prep_bytes + KSPLIT * NELEM * 4         // partials (33.6 MB)
                             + (size_t)KSPLIT * BATCH * SEQ * 4;       // L (0.26 MB)
    const bool prep  = (ws_size >= prep_bytes);
    const bool split = (ws_size >= split_bytes);

    unsigned short* Kbf = (unsigned short*)d_ws;
    unsigned short* Vtg = Kbf + NELEM;
    float* Opart = (float*)(Kbf + 2 * NELEM);
    float* Lpart = Opart + KSPLIT * NELEM;

    static int smem_cfged = 0;
    if (!smem_cfged) {
        (void)hipFuncSetAttribute((const void*)attn_fwd,
                                  hipFuncAttributeMaxDynamicSharedMemorySize, SMEM_BYTES);
        (void)hipFuncSetAttribute((const void*)attn_split,
                                  hipFuncAttributeMaxDynamicSharedMemorySize, SMEM_SPLIT);
        smem_cfged = 1;
    }

    if (prep && split) {
        prep_all<<<dim3(2048 + BATCH * 32 * 4), 256, 0, stream>>>(K, V, Kbf, Vtg);
        attn_split<<<dim3(BATCH * 32 * KSPLIT), 256, SMEM_SPLIT, stream>>>(Q, Kbf, Vtg, Opart, Lpart);
        merge_split<<<dim3(NELEM / (256 * 4)), 256, 0, stream>>>(Opart, Lpart, O);
    } else {
        attn_fwd<<<dim3(BATCH * (SEQ / 64)), 256, SMEM_BYTES, stream>>>(Q, K, V, O);
    }
}